// Round 8
// baseline (311.205 us; speedup 1.0000x reference)
//
#include <hip/hip_runtime.h>
#include <stdint.h>

// Problem constants
#define B_SZ   32
#define NIN    2312
#define NHID   512
#define NOUT   10
#define T_SZ   350
#define NW32   73                 // ceil(2312/32) bitmask words per input column
#define NW64   8                  // 512/64 ballot words per hidden column
#define NHALF  256                // output half-width for L2-resident W1
#define NROW   2313               // NIN + 1 dummy zero row (branch-free padding)

// psp (SRM) kernel eps[n] = CS * n * DS^n, DS = exp(-0.1), CS = e/10
#define DS_D   0.9048374180359595
#define DS2_D  0.8187307530779818      // exp(-0.2)
#define DS3_D  0.7408182206817179      // exp(-0.3)
#define DS4_D  0.6703200460356393      // exp(-0.4)
#define CS_D   0.2718281828459045
#define D100_D 4.5399929762484854e-05   // exp(-10) = DS^100
// refractory recurrence in fp32, exactly like the reference scan
#define DREF_F 0.36787944117144233f     // exp(-1)
#define CREF_F -54.36563656918091f      // -2*10*e

// R19 (proven, 295.9us): branch-free scan loops — clamped unconditional
// refill loads + cndmask select; register-collected uniform flushes.
// R20: R16's FIR seed re-landed WITH branch-free loads (R16's math passed
// absmax 0.0; its slowness was the guarded-load serialization R19 fixed).
// psp state seeded by a 100-tap FIR (no serial chain); refractory burn-in
// BURN=40 (error e^-40*|CREF| ~ 4e-16). Serial depth 150 -> 90 steps/chunk.
#define NCHUNK 7
#define CLEN   50
#define BURN   40                 // (CLEN+BURN) % NPF == 0
#define NPF    10                 // ring depth

// ---------------------------------------------------------------------------
// K12: fused bitpack (blocks 0..2335) + W1 half-split pack (2336..3503) +
//      dummy-zero-row fill (block 3504). Bitpack float4 streaming.
__global__ __launch_bounds__(384) void k12(const float* __restrict__ x,
                                           const float* __restrict__ W1,
                                           uint32_t* __restrict__ bits1,
                                           float* __restrict__ W1s) {
    __shared__ float lds[32 * T_SZ];   // 44.8 KB
    const int bid = blockIdx.x;
    const int tid = threadIdx.x;
    if (bid < NW32 * B_SZ) {
        // --- bitpack: block = (b, w); contiguous rowsx350 tile -> LDS -> pack
        const int w = bid % NW32;
        const int b = bid / NW32;
        const int rows = (NIN - (w << 5) < 32) ? (NIN - (w << 5)) : 32;  // 32 or 8
        const float* base = x + ((size_t)(b * NIN + (w << 5))) * T_SZ;
        const int nf4 = (rows * T_SZ) >> 2;     // rows even -> divisible by 4
        for (int f = tid; f < nf4; f += 384)
            ((float4*)lds)[f] = ((const float4*)base)[f];
        __syncthreads();
        if (tid < T_SZ) {
            uint32_t bits = 0;
            for (int j = 0; j < rows; ++j)
                bits |= (lds[j * T_SZ + tid] > 0.5f) ? (1u << j) : 0u;
            bits1[(size_t)(b * T_SZ + tid) * NW32 + w] = bits;
        }
    } else if (bid < NW32 * B_SZ + NW32 * 16) {
        // --- pack W1 [512, 2312] -> W1s[h][i][256], h = o>>8
        float (*tile)[33] = (float (*)[33])lds;
        const int bb = bid - NW32 * B_SZ;
        const int i0 = (bb % NW32) * 32, o0 = (bb / NW32) * 32;
        const int tx = tid & 31, ty = tid >> 5;  // ty 0..11
#pragma unroll
        for (int r = 0; r < 3; ++r) {
            int row = ty + 12 * r;
            if (row < 32) {
                int o = o0 + row, i = i0 + tx;
                if (i < NIN) tile[row][tx] = W1[(size_t)o * NIN + i];
            }
        }
        __syncthreads();
#pragma unroll
        for (int r = 0; r < 3; ++r) {
            int row = ty + 12 * r;
            if (row < 32) {
                int i = i0 + row, o = o0 + tx;
                if (i < NIN)
                    W1s[((size_t)(o >> 8) * NROW + i) * NHALF + (o & 255)] = tile[tx][row];
            }
        }
    } else {
        // --- dummy zero row i = NIN for both halves
        if (tid < NHALF) {
            W1s[((size_t)0 * NROW + NIN) * NHALF + tid] = 0.0f;
            W1s[((size_t)1 * NROW + NIN) * NHALF + tid] = 0.0f;
        }
    }
}

// ---------------------------------------------------------------------------
// K3: sparse dense1 (R6/R10 gather form — the measured optimum: 101us,
// 26.3 TB/s L2-gather = 76% of streaming ubench). Half-split for L2
// residency; single-wave shfl prefix scan; branch-free 4-deep pipelined row
// loop via dummy zero-row padding. R13: L2-HIT-SERVICE-RATE bound ->
// structural ceiling given the bit-exact sum order. Do not touch.
__global__ __launch_bounds__(256) void k3_dense1(const uint32_t* __restrict__ bits1,
                                                 const float* __restrict__ W1s,
                                                 float* __restrict__ z1ct) {
    __shared__ uint32_t words[128];
    __shared__ uint16_t pfx[80];
    __shared__ uint16_t idxbuf[NIN + 16];
    __shared__ float red[3][NHALF];
    __shared__ float fin[NHALF];

    const int id = blockIdx.x;
    const int h = (id >> 2) & 1;                  // XCD-affine half select
    const int bt = ((id >> 3) << 2) | (id & 3);   // b*350 + t (bijective)
    const int tid = threadIdx.x;
    const int wv = tid >> 6, lane = tid & 63;

    if (tid < 128) words[tid] = (tid < NW32) ? bits1[(size_t)bt * NW32 + tid] : 0u;
    __syncthreads();

    if (wv == 0) {
        uint32_t w0 = words[lane];
        uint32_t w1 = words[lane + 64];
        int p0 = __popc(w0), p1 = __popc(w1);
        int s0 = p0, s1 = p1;
#pragma unroll
        for (int off = 1; off < 64; off <<= 1) {
            int u0 = __shfl_up(s0, off);
            int u1 = __shfl_up(s1, off);
            if (lane >= off) { s0 += u0; s1 += u1; }
        }
        int tot0 = __shfl(s0, 63);
        pfx[lane] = (uint16_t)(s0 - p0);
        if (lane < 9) pfx[lane + 64] = (uint16_t)(tot0 + s1 - p1);
        if (lane == 8) pfx[73] = (uint16_t)(tot0 + s1);   // ntot
    }
    __syncthreads();

    const int ntot = pfx[73];
    const int npad = (ntot + 15) & ~15;
    if (tid < NW32) {
        uint32_t m = words[tid];
        int p = pfx[tid];
        while (m) {
            int j = __builtin_ctz(m);
            m &= m - 1;
            idxbuf[p++] = (uint16_t)((tid << 5) + j);
        }
    }
    if (tid >= 240) {                   // pad to multiple of 16 with zero row
        int k = tid - 240;
        if (ntot + k < npad) idxbuf[ntot + k] = (uint16_t)NIN;
    }
    __syncthreads();

    const float* Wh = W1s + (size_t)h * NROW * NHALF;
    float4 acc = make_float4(0.f, 0.f, 0.f, 0.f);
    for (int r = wv; r < npad; r += 16) {
        int i0 = idxbuf[r], i1 = idxbuf[r + 4], i2 = idxbuf[r + 8], i3 = idxbuf[r + 12];
        float4 v0 = ((const float4*)(Wh + (size_t)i0 * NHALF))[lane];
        float4 v1 = ((const float4*)(Wh + (size_t)i1 * NHALF))[lane];
        float4 v2 = ((const float4*)(Wh + (size_t)i2 * NHALF))[lane];
        float4 v3 = ((const float4*)(Wh + (size_t)i3 * NHALF))[lane];
        acc.x += v0.x; acc.y += v0.y; acc.z += v0.z; acc.w += v0.w;
        acc.x += v1.x; acc.y += v1.y; acc.z += v1.z; acc.w += v1.w;
        acc.x += v2.x; acc.y += v2.y; acc.z += v2.z; acc.w += v2.w;
        acc.x += v3.x; acc.y += v3.y; acc.z += v3.z; acc.w += v3.w;
    }
    if (wv > 0) ((float4*)red[wv - 1])[lane] = acc;
    __syncthreads();
    if (wv == 0) {
        float4 a1 = ((float4*)red[0])[lane];
        float4 a2 = ((float4*)red[1])[lane];
        float4 a3 = ((float4*)red[2])[lane];
        acc.x = ((acc.x + a1.x) + a2.x) + a3.x;
        acc.y = ((acc.y + a1.y) + a2.y) + a3.y;
        acc.z = ((acc.z + a1.z) + a2.z) + a3.z;
        acc.w = ((acc.w + a1.w) + a2.w) + a3.w;
        ((float4*)fin)[lane] = acc;
    }
    __syncthreads();
    const int och = (h << 8) + tid;
    const int oc = och >> 6, l6 = och & 63;
    const int b = bt / T_SZ, t = bt - b * T_SZ;
    z1ct[((size_t)(b * NW64 + oc) * T_SZ + t) * 64 + l6] = fin[tid];
}

// ---------------------------------------------------------------------------
// K45: fused layer-1 scan + dense2. R19 branch-free scan + R20 branch-free
// FIR seed (math identical to R16, which passed absmax 0.0).
__global__ __launch_bounds__(512) void k45(const float* __restrict__ z1ct,
                                           const float* __restrict__ W2,
                                           float* __restrict__ z2ct) {
    __shared__ float W2s[NHID * NOUT];      // [c][o], 20 KB
    __shared__ uint64_t sw[CLEN][NW64];     // s1 ballot words for my 50 t's
    const int tid = threadIdx.x;
    const int wv = tid >> 6, lane = tid & 63;
    const int b = blockIdx.x / NCHUNK;
    const int ck = blockIdx.x % NCHUNK;
    const int tstart = ck * CLEN;
    const int tend = tstart + CLEN;
    const int t0 = (ck == 0) ? 0 : tstart - BURN;

    for (int k = tid; k < NHID * NOUT; k += 512) {
        int c = k / NOUT, o = k - c * NOUT;
        W2s[k] = W2[(size_t)o * NHID + c];
    }

    const float* base = z1ct + (size_t)(b * NW64 + wv) * T_SZ * 64 + lane;
    double A = 0.0, Bs = 0.0, A2 = 0.0, Bs2 = 0.0;
    float ra = 0.0f, rb = 0.0f;
    const double TAIL = D100_D * CS_D;

    if (ck != 0) {
        // ---- direct 100-tap FIR seed of state-after-(t0-1), branch-free
        const int hi1 = t0 - 1;        // window for (A, Bs)
        const int hi2 = t0 - 101;      // window for (A2, Bs2): xd = x(t-100)
        double F0=0,F1=0,F2=0,F3=0, G0=0,G1=0,G2=0,G3=0;
        double P0=0,P1=0,P2=0,P3=0, Q0=0,Q1=0,Q2=0,Q3=0;
#pragma unroll
        for (int q = 0; q < 25; ++q) {
            const int ta3 = hi1 - 99 + 4 * q;
            const int c0 = (ta3     >= 0) ? ta3     : 0;
            const int c1 = (ta3 + 1 >= 0) ? ta3 + 1 : 0;
            const int c2 = (ta3 + 2 >= 0) ? ta3 + 2 : 0;
            const int c3 = (ta3 + 3 >= 0) ? ta3 + 3 : 0;
            float v0 = base[(size_t)c0 * 64];
            float v1 = base[(size_t)c1 * 64];
            float v2 = base[(size_t)c2 * 64];
            float v3 = base[(size_t)c3 * 64];
            float x3 = (ta3     >= 0) ? v0 : 0.f;
            float x2 = (ta3 + 1 >= 0) ? v1 : 0.f;
            float x1 = (ta3 + 2 >= 0) ? v2 : 0.f;
            float x0 = (ta3 + 3 >= 0) ? v3 : 0.f;
            G3 = DS4_D * G3 + DS4_D * F3; F3 = DS4_D * F3 + (double)x3;
            G2 = DS4_D * G2 + DS4_D * F2; F2 = DS4_D * F2 + (double)x2;
            G1 = DS4_D * G1 + DS4_D * F1; F1 = DS4_D * F1 + (double)x1;
            G0 = DS4_D * G0 + DS4_D * F0; F0 = DS4_D * F0 + (double)x0;
            const int tb3 = hi2 - 99 + 4 * q;
            const int d0 = (tb3     >= 0) ? tb3     : 0;
            const int d1 = (tb3 + 1 >= 0) ? tb3 + 1 : 0;
            const int d2 = (tb3 + 2 >= 0) ? tb3 + 2 : 0;
            const int d3 = (tb3 + 3 >= 0) ? tb3 + 3 : 0;
            float w0 = base[(size_t)d0 * 64];
            float w1 = base[(size_t)d1 * 64];
            float w2 = base[(size_t)d2 * 64];
            float w3 = base[(size_t)d3 * 64];
            float y3 = (tb3     >= 0) ? w0 : 0.f;
            float y2 = (tb3 + 1 >= 0) ? w1 : 0.f;
            float y1 = (tb3 + 2 >= 0) ? w2 : 0.f;
            float y0 = (tb3 + 3 >= 0) ? w3 : 0.f;
            Q3 = DS4_D * Q3 + DS4_D * P3; P3 = DS4_D * P3 + (double)y3;
            Q2 = DS4_D * Q2 + DS4_D * P2; P2 = DS4_D * P2 + (double)y2;
            Q1 = DS4_D * Q1 + DS4_D * P1; P1 = DS4_D * P1 + (double)y1;
            Q0 = DS4_D * Q0 + DS4_D * P0; P0 = DS4_D * P0 + (double)y0;
        }
        A   = F0 + DS_D * F1 + DS2_D * F2 + DS3_D * F3;
        Bs  = 4.0 * G0 + DS_D * (F1 + 4.0 * G1)
            + DS2_D * (2.0 * F2 + 4.0 * G2) + DS3_D * (3.0 * F3 + 4.0 * G3);
        A2  = P0 + DS_D * P1 + DS2_D * P2 + DS3_D * P3;
        Bs2 = 4.0 * Q0 + DS_D * (P1 + 4.0 * Q1)
            + DS2_D * (2.0 * P2 + 4.0 * Q2) + DS3_D * (3.0 * P3 + 4.0 * Q3);
    }

    // ---- scan: burn-in (BURN steps, refractory settling) + emitted chunk
    float xb[NPF], xdb[NPF];
#pragma unroll
    for (int i = 0; i < NPF; ++i) {
        const int t = t0 + i;                       // valid
        xb[i] = base[(size_t)t * 64];
        const int td = t - 100;
        const int tdc = (td >= 0) ? td : 0;
        float vd = base[(size_t)tdc * 64];
        xdb[i] = (td >= 0) ? vd : 0.0f;
    }
    for (int tb = t0; tb < tend; tb += NPF) {
        uint64_t mb[NPF];
#pragma unroll
        for (int i = 0; i < NPF; ++i) {
            const int t = tb + i;
            float x = xb[i], xd = xdb[i];
            const int tn = t + NPF;
            const int tcl = (tn < T_SZ) ? tn : (T_SZ - 1);
            float vb = base[(size_t)tcl * 64];
            xb[i] = (tn < T_SZ) ? vb : 0.0f;
            const int td = tn - 100;
            const int tdc = (td >= 0) ? td : 0;
            float vd = base[(size_t)tdc * 64];
            xdb[i] = (td >= 0) ? vd : 0.0f;
            Bs = DS_D * Bs + DS_D * A;
            A = DS_D * A + (double)x;
            Bs2 = DS_D * Bs2 + DS_D * A2;
            A2 = DS_D * A2 + (double)xd;
            double y = CS_D * Bs - TAIL * (Bs2 + 100.0 * A2);
            float u = (float)y + CREF_F * rb;
            float s = (u >= 10.0f) ? 1.0f : 0.0f;
            float ran = DREF_F * ra + s;
            float rbn = DREF_F * rb + DREF_F * ra;
            ra = ran; rb = rbn;
            mb[i] = __ballot(s != 0.0f);
        }
        // uniform per-tb flush: (tstart - t0) % NPF == 0
        if (tb >= tstart && lane == 0) {
#pragma unroll
            for (int i = 0; i < NPF; ++i)
                sw[tb - tstart + i][wv] = mb[i];
        }
    }
    __syncthreads();

    // ---- dense2 for my 50 t's (same order as R1 -> bit-identical)
    if (tid < CLEN * NOUT) {                // 500 of 512
        const int tr = tid / NOUT;
        const int o = tid - tr * NOUT;
        const int t = tstart + tr;
        float acc = 0.f;
#pragma unroll
        for (int w2 = 0; w2 < NW64; ++w2) {
            uint64_t m = sw[tr][w2];
            while (m) {
                int j = __builtin_ctzll(m);
                m &= m - 1;
                acc += W2s[((w2 << 6) + j) * NOUT + o];
            }
        }
        const int bo = b * NOUT + o;
        z2ct[((size_t)(bo >> 6) * T_SZ + t) * 64 + (bo & 63)] = acc;
    }
}

// ---------------------------------------------------------------------------
// K6: layer-2 psp+refractory scan, chunked, R19 branch-free + R20 FIR seed.
__global__ __launch_bounds__(64) void k6_fir_scan2(const float* __restrict__ z2ct,
                                                   float* __restrict__ out) {
    const int lane = threadIdx.x;
    const int g = blockIdx.x / NCHUNK;    // bo group 0..4
    const int ck = blockIdx.x % NCHUNK;
    const int tstart = ck * CLEN;
    const int tend = tstart + CLEN;
    const int t0 = (ck == 0) ? 0 : tstart - BURN;
    const int bo = (g << 6) + lane;       // 0..319
    const float* base = z2ct + (size_t)g * T_SZ * 64 + lane;
    float* op = out + (size_t)bo * T_SZ;
    double A = 0.0, Bs = 0.0, A2 = 0.0, Bs2 = 0.0;
    float ra = 0.0f, rb = 0.0f;
    const double TAIL = D100_D * CS_D;

    if (ck != 0) {
        const int hi1 = t0 - 1;
        const int hi2 = t0 - 101;
        double F0=0,F1=0,F2=0,F3=0, G0=0,G1=0,G2=0,G3=0;
        double P0=0,P1=0,P2=0,P3=0, Q0=0,Q1=0,Q2=0,Q3=0;
#pragma unroll
        for (int q = 0; q < 25; ++q) {
            const int ta3 = hi1 - 99 + 4 * q;
            const int c0 = (ta3     >= 0) ? ta3     : 0;
            const int c1 = (ta3 + 1 >= 0) ? ta3 + 1 : 0;
            const int c2 = (ta3 + 2 >= 0) ? ta3 + 2 : 0;
            const int c3 = (ta3 + 3 >= 0) ? ta3 + 3 : 0;
            float v0 = base[(size_t)c0 * 64];
            float v1 = base[(size_t)c1 * 64];
            float v2 = base[(size_t)c2 * 64];
            float v3 = base[(size_t)c3 * 64];
            float x3 = (ta3     >= 0) ? v0 : 0.f;
            float x2 = (ta3 + 1 >= 0) ? v1 : 0.f;
            float x1 = (ta3 + 2 >= 0) ? v2 : 0.f;
            float x0 = (ta3 + 3 >= 0) ? v3 : 0.f;
            G3 = DS4_D * G3 + DS4_D * F3; F3 = DS4_D * F3 + (double)x3;
            G2 = DS4_D * G2 + DS4_D * F2; F2 = DS4_D * F2 + (double)x2;
            G1 = DS4_D * G1 + DS4_D * F1; F1 = DS4_D * F1 + (double)x1;
            G0 = DS4_D * G0 + DS4_D * F0; F0 = DS4_D * F0 + (double)x0;
            const int tb3 = hi2 - 99 + 4 * q;
            const int d0 = (tb3     >= 0) ? tb3     : 0;
            const int d1 = (tb3 + 1 >= 0) ? tb3 + 1 : 0;
            const int d2 = (tb3 + 2 >= 0) ? tb3 + 2 : 0;
            const int d3 = (tb3 + 3 >= 0) ? tb3 + 3 : 0;
            float w0 = base[(size_t)d0 * 64];
            float w1 = base[(size_t)d1 * 64];
            float w2 = base[(size_t)d2 * 64];
            float w3 = base[(size_t)d3 * 64];
            float y3 = (tb3     >= 0) ? w0 : 0.f;
            float y2 = (tb3 + 1 >= 0) ? w1 : 0.f;
            float y1 = (tb3 + 2 >= 0) ? w2 : 0.f;
            float y0 = (tb3 + 3 >= 0) ? w3 : 0.f;
            Q3 = DS4_D * Q3 + DS4_D * P3; P3 = DS4_D * P3 + (double)y3;
            Q2 = DS4_D * Q2 + DS4_D * P2; P2 = DS4_D * P2 + (double)y2;
            Q1 = DS4_D * Q1 + DS4_D * P1; P1 = DS4_D * P1 + (double)y1;
            Q0 = DS4_D * Q0 + DS4_D * P0; P0 = DS4_D * P0 + (double)y0;
        }
        A   = F0 + DS_D * F1 + DS2_D * F2 + DS3_D * F3;
        Bs  = 4.0 * G0 + DS_D * (F1 + 4.0 * G1)
            + DS2_D * (2.0 * F2 + 4.0 * G2) + DS3_D * (3.0 * F3 + 4.0 * G3);
        A2  = P0 + DS_D * P1 + DS2_D * P2 + DS3_D * P3;
        Bs2 = 4.0 * Q0 + DS_D * (P1 + 4.0 * Q1)
            + DS2_D * (2.0 * P2 + 4.0 * Q2) + DS3_D * (3.0 * P3 + 4.0 * Q3);
    }

    float xb[NPF], xdb[NPF];
#pragma unroll
    for (int i = 0; i < NPF; ++i) {
        const int t = t0 + i;
        xb[i] = base[(size_t)t * 64];
        const int td = t - 100;
        const int tdc = (td >= 0) ? td : 0;
        float vd = base[(size_t)tdc * 64];
        xdb[i] = (td >= 0) ? vd : 0.0f;
    }
    for (int tb = t0; tb < tend; tb += NPF) {
        float sb[NPF];
#pragma unroll
        for (int i = 0; i < NPF; ++i) {
            const int t = tb + i;
            float x = xb[i], xd = xdb[i];
            const int tn = t + NPF;
            const int tcl = (tn < T_SZ) ? tn : (T_SZ - 1);
            float vb = base[(size_t)tcl * 64];
            xb[i] = (tn < T_SZ) ? vb : 0.0f;
            const int td = tn - 100;
            const int tdc = (td >= 0) ? td : 0;
            float vd = base[(size_t)tdc * 64];
            xdb[i] = (td >= 0) ? vd : 0.0f;
            Bs = DS_D * Bs + DS_D * A;
            A = DS_D * A + (double)x;
            Bs2 = DS_D * Bs2 + DS_D * A2;
            A2 = DS_D * A2 + (double)xd;
            double y = CS_D * Bs - TAIL * (Bs2 + 100.0 * A2);
            float u = (float)y + CREF_F * rb;
            float s = (u >= 10.0f) ? 1.0f : 0.0f;
            float ran = DREF_F * ra + s;
            float rbn = DREF_F * rb + DREF_F * ra;
            ra = ran; rb = rbn;
            sb[i] = s;
        }
        if (tb >= tstart) {                 // uniform per-tb flush
#pragma unroll
            for (int i = 0; i < NPF; ++i)
                op[tb + i] = sb[i];
        }
    }
}

// ---------------------------------------------------------------------------
extern "C" void kernel_launch(void* const* d_in, const int* in_sizes, int n_in,
                              void* d_out, int out_size, void* d_ws, size_t ws_size,
                              hipStream_t stream) {
    const float* spikeInput = (const float*)d_in[0];  // [32, 2312, 350]
    const float* W1 = (const float*)d_in[1];          // [512, 2312]
    const float* W2 = (const float*)d_in[2];          // [10, 512]
    float* out = (float*)d_out;                       // [32, 10, 350]

    char* ws = (char*)d_ws;
    float* W1s = (float*)(ws + 0);                        //  4,737,024 B (2313 rows x 2 halves)
    uint32_t* bits1 = (uint32_t*)(ws + 4737024);          //  3,270,400 B
    float* z1ct = (float*)(ws + 8007424);                 // 22,937,600 B
    // z2ct aliases bits1's region: bits1 is dead after k3, z2ct written by k45.
    float* z2ct = (float*)(ws + 4737024);                 //    448,000 B (alias)
    // total: 30,945,024 B

    k12<<<NW32 * B_SZ + NW32 * 16 + 1, 384, 0, stream>>>(spikeInput, W1, bits1, W1s);
    k3_dense1<<<B_SZ * T_SZ * 2, 256, 0, stream>>>(bits1, W1s, z1ct);
    k45<<<B_SZ * NCHUNK, 512, 0, stream>>>(z1ct, W2, z2ct);
    k6_fir_scan2<<<5 * NCHUNK, 64, 0, stream>>>(z2ct, out);
}

// Round 10
// 303.075 us; speedup vs baseline: 1.0268x; 1.0268x over previous
//
#include <hip/hip_runtime.h>
#include <stdint.h>

// Problem constants
#define B_SZ   32
#define NIN    2312
#define NHID   512
#define NOUT   10
#define T_SZ   350
#define NW32   73                 // ceil(2312/32) bitmask words per input column
#define NW64   8                  // 512/64 ballot words per hidden column
#define NHALF  256                // output half-width for L2-resident W1
#define NROW   2313               // NIN + 1 dummy zero row (branch-free padding)

// psp (SRM) kernel eps[n] = CS * n * DS^n, DS = exp(-0.1), CS = e/10
#define DS_D   0.9048374180359595
#define CS_D   0.2718281828459045
#define D100_D 4.5399929762484854e-05   // exp(-10) = DS^100
// refractory recurrence in fp32, exactly like the reference scan
#define DREF_F 0.36787944117144233f     // exp(-1)
#define CREF_F -54.36563656918091f      // -2*10*e

// R19 (proven 295.9us): branch-free scan loops — clamped unconditional
// refill loads + cndmask select; register-collected uniform flushes.
// R20 post-mortem: FIR seed regressed AGAIN (+15us branch-free; +48us
// guarded) — 400 chained f64 FMAs + 32 live VGPRs cost more than the 60
// serial steps saved. Seed permanently abandoned; exact 100-step warm-up.
// R21 (resubmitted R22 after container failure — untested, unchanged):
// chunk geometry only. R6<->R7 delta => ~250 cy/step >> ~40 cy issue
// => scans are f64 DEP-LATENCY-bound at 2 waves/SIMD (224 blocks ~ 1/CU).
// NCHUNK 7->14 (CLEN 25, NPF 5): k45 448 blocks (~4 waves/SIMD), serial
// depth 150->125; k6 70 blocks. Per-step math & order unchanged -> output
// byte-identical to R7/R1.
#define NCHUNK 14
#define CLEN   25                 // CLEN % NPF == 0; 100 % NPF == 0
#define NPF    5                  // ring depth

// ---------------------------------------------------------------------------
// K12: fused bitpack (blocks 0..2335) + W1 half-split pack (2336..3503) +
//      dummy-zero-row fill (block 3504). Bitpack float4 streaming.
__global__ __launch_bounds__(384) void k12(const float* __restrict__ x,
                                           const float* __restrict__ W1,
                                           uint32_t* __restrict__ bits1,
                                           float* __restrict__ W1s) {
    __shared__ float lds[32 * T_SZ];   // 44.8 KB
    const int bid = blockIdx.x;
    const int tid = threadIdx.x;
    if (bid < NW32 * B_SZ) {
        // --- bitpack: block = (b, w); contiguous rowsx350 tile -> LDS -> pack
        const int w = bid % NW32;
        const int b = bid / NW32;
        const int rows = (NIN - (w << 5) < 32) ? (NIN - (w << 5)) : 32;  // 32 or 8
        const float* base = x + ((size_t)(b * NIN + (w << 5))) * T_SZ;
        const int nf4 = (rows * T_SZ) >> 2;     // rows even -> divisible by 4
        for (int f = tid; f < nf4; f += 384)
            ((float4*)lds)[f] = ((const float4*)base)[f];
        __syncthreads();
        if (tid < T_SZ) {
            uint32_t bits = 0;
            for (int j = 0; j < rows; ++j)
                bits |= (lds[j * T_SZ + tid] > 0.5f) ? (1u << j) : 0u;
            bits1[(size_t)(b * T_SZ + tid) * NW32 + w] = bits;
        }
    } else if (bid < NW32 * B_SZ + NW32 * 16) {
        // --- pack W1 [512, 2312] -> W1s[h][i][256], h = o>>8
        float (*tile)[33] = (float (*)[33])lds;
        const int bb = bid - NW32 * B_SZ;
        const int i0 = (bb % NW32) * 32, o0 = (bb / NW32) * 32;
        const int tx = tid & 31, ty = tid >> 5;  // ty 0..11
#pragma unroll
        for (int r = 0; r < 3; ++r) {
            int row = ty + 12 * r;
            if (row < 32) {
                int o = o0 + row, i = i0 + tx;
                if (i < NIN) tile[row][tx] = W1[(size_t)o * NIN + i];
            }
        }
        __syncthreads();
#pragma unroll
        for (int r = 0; r < 3; ++r) {
            int row = ty + 12 * r;
            if (row < 32) {
                int i = i0 + row, o = o0 + tx;
                if (i < NIN)
                    W1s[((size_t)(o >> 8) * NROW + i) * NHALF + (o & 255)] = tile[tx][row];
            }
        }
    } else {
        // --- dummy zero row i = NIN for both halves
        if (tid < NHALF) {
            W1s[((size_t)0 * NROW + NIN) * NHALF + tid] = 0.0f;
            W1s[((size_t)1 * NROW + NIN) * NHALF + tid] = 0.0f;
        }
    }
}

// ---------------------------------------------------------------------------
// K3: sparse dense1 (R6/R10 gather form — the measured optimum: 101us,
// 26.3 TB/s L2-gather = 76% of streaming ubench). Half-split for L2
// residency; single-wave shfl prefix scan; branch-free 4-deep pipelined row
// loop via dummy zero-row padding. R13: L2-HIT-SERVICE-RATE bound ->
// structural ceiling given the bit-exact sum order. Do not touch.
__global__ __launch_bounds__(256) void k3_dense1(const uint32_t* __restrict__ bits1,
                                                 const float* __restrict__ W1s,
                                                 float* __restrict__ z1ct) {
    __shared__ uint32_t words[128];
    __shared__ uint16_t pfx[80];
    __shared__ uint16_t idxbuf[NIN + 16];
    __shared__ float red[3][NHALF];
    __shared__ float fin[NHALF];

    const int id = blockIdx.x;
    const int h = (id >> 2) & 1;                  // XCD-affine half select
    const int bt = ((id >> 3) << 2) | (id & 3);   // b*350 + t (bijective)
    const int tid = threadIdx.x;
    const int wv = tid >> 6, lane = tid & 63;

    if (tid < 128) words[tid] = (tid < NW32) ? bits1[(size_t)bt * NW32 + tid] : 0u;
    __syncthreads();

    if (wv == 0) {
        uint32_t w0 = words[lane];
        uint32_t w1 = words[lane + 64];
        int p0 = __popc(w0), p1 = __popc(w1);
        int s0 = p0, s1 = p1;
#pragma unroll
        for (int off = 1; off < 64; off <<= 1) {
            int u0 = __shfl_up(s0, off);
            int u1 = __shfl_up(s1, off);
            if (lane >= off) { s0 += u0; s1 += u1; }
        }
        int tot0 = __shfl(s0, 63);
        pfx[lane] = (uint16_t)(s0 - p0);
        if (lane < 9) pfx[lane + 64] = (uint16_t)(tot0 + s1 - p1);
        if (lane == 8) pfx[73] = (uint16_t)(tot0 + s1);   // ntot
    }
    __syncthreads();

    const int ntot = pfx[73];
    const int npad = (ntot + 15) & ~15;
    if (tid < NW32) {
        uint32_t m = words[tid];
        int p = pfx[tid];
        while (m) {
            int j = __builtin_ctz(m);
            m &= m - 1;
            idxbuf[p++] = (uint16_t)((tid << 5) + j);
        }
    }
    if (tid >= 240) {                   // pad to multiple of 16 with zero row
        int k = tid - 240;
        if (ntot + k < npad) idxbuf[ntot + k] = (uint16_t)NIN;
    }
    __syncthreads();

    const float* Wh = W1s + (size_t)h * NROW * NHALF;
    float4 acc = make_float4(0.f, 0.f, 0.f, 0.f);
    for (int r = wv; r < npad; r += 16) {
        int i0 = idxbuf[r], i1 = idxbuf[r + 4], i2 = idxbuf[r + 8], i3 = idxbuf[r + 12];
        float4 v0 = ((const float4*)(Wh + (size_t)i0 * NHALF))[lane];
        float4 v1 = ((const float4*)(Wh + (size_t)i1 * NHALF))[lane];
        float4 v2 = ((const float4*)(Wh + (size_t)i2 * NHALF))[lane];
        float4 v3 = ((const float4*)(Wh + (size_t)i3 * NHALF))[lane];
        acc.x += v0.x; acc.y += v0.y; acc.z += v0.z; acc.w += v0.w;
        acc.x += v1.x; acc.y += v1.y; acc.z += v1.z; acc.w += v1.w;
        acc.x += v2.x; acc.y += v2.y; acc.z += v2.z; acc.w += v2.w;
        acc.x += v3.x; acc.y += v3.y; acc.z += v3.z; acc.w += v3.w;
    }
    if (wv > 0) ((float4*)red[wv - 1])[lane] = acc;
    __syncthreads();
    if (wv == 0) {
        float4 a1 = ((float4*)red[0])[lane];
        float4 a2 = ((float4*)red[1])[lane];
        float4 a3 = ((float4*)red[2])[lane];
        acc.x = ((acc.x + a1.x) + a2.x) + a3.x;
        acc.y = ((acc.y + a1.y) + a2.y) + a3.y;
        acc.z = ((acc.z + a1.z) + a2.z) + a3.z;
        acc.w = ((acc.w + a1.w) + a2.w) + a3.w;
        ((float4*)fin)[lane] = acc;
    }
    __syncthreads();
    const int och = (h << 8) + tid;
    const int oc = och >> 6, l6 = och & 63;
    const int b = bt / T_SZ, t = bt - b * T_SZ;
    z1ct[((size_t)(b * NW64 + oc) * T_SZ + t) * 64 + l6] = fin[tid];
}

// ---------------------------------------------------------------------------
// K45: fused layer-1 scan + dense2 (R7-proven form; R21 = chunk geometry
// only). Branch-free refills; exact 100-step warm-up; uniform flushes.
__global__ __launch_bounds__(512) void k45(const float* __restrict__ z1ct,
                                           const float* __restrict__ W2,
                                           float* __restrict__ z2ct) {
    __shared__ float W2s[NHID * NOUT];      // [c][o], 20 KB
    __shared__ uint64_t sw[CLEN][NW64];     // s1 ballot words for my 25 t's
    const int tid = threadIdx.x;
    const int wv = tid >> 6, lane = tid & 63;
    const int b = blockIdx.x / NCHUNK;
    const int ck = blockIdx.x % NCHUNK;
    const int tstart = ck * CLEN;
    const int tend = tstart + CLEN;
    const int t0 = (tstart >= 100) ? tstart - 100 : 0;

    for (int k = tid; k < NHID * NOUT; k += 512) {
        int c = k / NOUT, o = k - c * NOUT;
        W2s[k] = W2[(size_t)o * NHID + c];
    }

    // ---- layer-1 chunked scan (identical math to R1/R7)
    const float* base = z1ct + (size_t)(b * NW64 + wv) * T_SZ * 64 + lane;
    double A = 0.0, Bs = 0.0, A2 = 0.0, Bs2 = 0.0;
    float ra = 0.0f, rb = 0.0f;
    const double TAIL = D100_D * CS_D;
    float xb[NPF], xdb[NPF];
#pragma unroll
    for (int i = 0; i < NPF; ++i) {
        const int t = t0 + i;                       // < 350: always valid
        xb[i] = base[(size_t)t * 64];
        const int td = t - 100;
        const int tdc = (td >= 0) ? td : 0;
        float vd = base[(size_t)tdc * 64];          // unconditional
        xdb[i] = (td >= 0) ? vd : 0.0f;             // select, no branch
    }
    for (int tb = t0; tb < tend; tb += NPF) {
        uint64_t mb[NPF];
#pragma unroll
        for (int i = 0; i < NPF; ++i) {
            const int t = tb + i;
            float x = xb[i], xd = xdb[i];
            const int tn = t + NPF;
            const int tcl = (tn < T_SZ) ? tn : (T_SZ - 1);
            float vb = base[(size_t)tcl * 64];      // unconditional (clamped)
            xb[i] = (tn < T_SZ) ? vb : 0.0f;
            const int td = tn - 100;
            const int tdc = (td >= 0) ? td : 0;
            float vd = base[(size_t)tdc * 64];      // unconditional (clamped)
            xdb[i] = (td >= 0) ? vd : 0.0f;
            Bs = DS_D * Bs + DS_D * A;
            A = DS_D * A + (double)x;
            Bs2 = DS_D * Bs2 + DS_D * A2;
            A2 = DS_D * A2 + (double)xd;
            double y = CS_D * Bs - TAIL * (Bs2 + 100.0 * A2);
            float u = (float)y + CREF_F * rb;
            float s = (u >= 10.0f) ? 1.0f : 0.0f;
            float ran = DREF_F * ra + s;
            float rbn = DREF_F * rb + DREF_F * ra;
            ra = ran; rb = rbn;
            mb[i] = __ballot(s != 0.0f);
        }
        // uniform per-tb flush: (tstart - t0) % NPF == 0
        if (tb >= tstart && lane == 0) {
#pragma unroll
            for (int i = 0; i < NPF; ++i)
                sw[tb - tstart + i][wv] = mb[i];
        }
    }
    __syncthreads();

    // ---- dense2 for my 25 t's (same per-t order as R1 -> bit-identical)
    if (tid < CLEN * NOUT) {                // 250 of 512
        const int tr = tid / NOUT;
        const int o = tid - tr * NOUT;
        const int t = tstart + tr;
        float acc = 0.f;
#pragma unroll
        for (int w2 = 0; w2 < NW64; ++w2) {
            uint64_t m = sw[tr][w2];
            while (m) {
                int j = __builtin_ctzll(m);
                m &= m - 1;
                acc += W2s[((w2 << 6) + j) * NOUT + o];
            }
        }
        const int bo = b * NOUT + o;
        z2ct[((size_t)(bo >> 6) * T_SZ + t) * 64 + (bo & 63)] = acc;
    }
}

// ---------------------------------------------------------------------------
// K6: fused psp-IIR + refractory scan, layer 2, chunked (R7-proven form;
// R21 chunk geometry only). Branch-free refills + uniform flushes.
__global__ __launch_bounds__(64) void k6_fir_scan2(const float* __restrict__ z2ct,
                                                   float* __restrict__ out) {
    const int lane = threadIdx.x;
    const int g = blockIdx.x / NCHUNK;    // bo group 0..4
    const int ck = blockIdx.x % NCHUNK;
    const int tstart = ck * CLEN;
    const int tend = tstart + CLEN;
    const int t0 = (tstart >= 100) ? tstart - 100 : 0;
    const int bo = (g << 6) + lane;       // 0..319
    const float* base = z2ct + (size_t)g * T_SZ * 64 + lane;
    float* op = out + (size_t)bo * T_SZ;
    double A = 0.0, Bs = 0.0, A2 = 0.0, Bs2 = 0.0;
    float ra = 0.0f, rb = 0.0f;
    const double TAIL = D100_D * CS_D;
    float xb[NPF], xdb[NPF];
#pragma unroll
    for (int i = 0; i < NPF; ++i) {
        const int t = t0 + i;
        xb[i] = base[(size_t)t * 64];
        const int td = t - 100;
        const int tdc = (td >= 0) ? td : 0;
        float vd = base[(size_t)tdc * 64];
        xdb[i] = (td >= 0) ? vd : 0.0f;
    }
    for (int tb = t0; tb < tend; tb += NPF) {
        float sb[NPF];
#pragma unroll
        for (int i = 0; i < NPF; ++i) {
            const int t = tb + i;
            float x = xb[i], xd = xdb[i];
            const int tn = t + NPF;
            const int tcl = (tn < T_SZ) ? tn : (T_SZ - 1);
            float vb = base[(size_t)tcl * 64];
            xb[i] = (tn < T_SZ) ? vb : 0.0f;
            const int td = tn - 100;
            const int tdc = (td >= 0) ? td : 0;
            float vd = base[(size_t)tdc * 64];
            xdb[i] = (td >= 0) ? vd : 0.0f;
            Bs = DS_D * Bs + DS_D * A;
            A = DS_D * A + (double)x;
            Bs2 = DS_D * Bs2 + DS_D * A2;
            A2 = DS_D * A2 + (double)xd;
            double y = CS_D * Bs - TAIL * (Bs2 + 100.0 * A2);
            float u = (float)y + CREF_F * rb;
            float s = (u >= 10.0f) ? 1.0f : 0.0f;
            float ran = DREF_F * ra + s;
            float rbn = DREF_F * rb + DREF_F * ra;
            ra = ran; rb = rbn;
            sb[i] = s;
        }
        if (tb >= tstart) {                 // uniform per-tb flush
#pragma unroll
            for (int i = 0; i < NPF; ++i)
                op[tb + i] = sb[i];
        }
    }
}

// ---------------------------------------------------------------------------
extern "C" void kernel_launch(void* const* d_in, const int* in_sizes, int n_in,
                              void* d_out, int out_size, void* d_ws, size_t ws_size,
                              hipStream_t stream) {
    const float* spikeInput = (const float*)d_in[0];  // [32, 2312, 350]
    const float* W1 = (const float*)d_in[1];          // [512, 2312]
    const float* W2 = (const float*)d_in[2];          // [10, 512]
    float* out = (float*)d_out;                       // [32, 10, 350]

    char* ws = (char*)d_ws;
    float* W1s = (float*)(ws + 0);                        //  4,737,024 B (2313 rows x 2 halves)
    uint32_t* bits1 = (uint32_t*)(ws + 4737024);          //  3,270,400 B
    float* z1ct = (float*)(ws + 8007424);                 // 22,937,600 B
    // z2ct aliases bits1's region: bits1 is dead after k3, z2ct written by k45.
    float* z2ct = (float*)(ws + 4737024);                 //    448,000 B (alias)
    // total: 30,945,024 B

    k12<<<NW32 * B_SZ + NW32 * 16 + 1, 384, 0, stream>>>(spikeInput, W1, bits1, W1s);
    k3_dense1<<<B_SZ * T_SZ * 2, 256, 0, stream>>>(bits1, W1s, z1ct);
    k45<<<B_SZ * NCHUNK, 512, 0, stream>>>(z1ct, W2, z2ct);
    k6_fir_scan2<<<5 * NCHUNK, 64, 0, stream>>>(z2ct, out);
}

// Round 11
// 296.807 us; speedup vs baseline: 1.0485x; 1.0211x over previous
//
#include <hip/hip_runtime.h>
#include <stdint.h>

// Problem constants
#define B_SZ   32
#define NIN    2312
#define NHID   512
#define NOUT   10
#define T_SZ   350
#define NW32   73                 // ceil(2312/32) bitmask words per input column
#define NW64   8                  // 512/64 ballot words per hidden column
#define NHALF  256                // output half-width for L2-resident W1
#define NROW   2313               // NIN + 1 dummy zero row (branch-free padding)

// psp (SRM) kernel eps[n] = CS * n * DS^n, DS = exp(-0.1), CS = e/10
#define DS_D   0.9048374180359595
#define CS_D   0.2718281828459045
#define D100_D 4.5399929762484854e-05   // exp(-10) = DS^100
// refractory recurrence in fp32, exactly like the reference scan
#define DREF_F 0.36787944117144233f     // exp(-1)
#define CREF_F -54.36563656918091f      // -2*10*e

// R19 (proven 295.9us): branch-free scan loops. R20: FIR seed abandoned
// (regressed twice). R21 post-mortem: NCHUNK 14 regressed +7us — extra
// chunks repeat the 100-step warm-up (900->1500 total steps); chunk count
// is a dead axis. Reverted to NCHUNK=7.
// R23: dual-chain k45 — 4 waves x 2 channel-groups/lane. Two independent
// recurrences interleaved per lane double dep-chain ILP with ZERO extra
// work (the R21 mistake inverted). Per-chain math/ballot/dense2 order
// unchanged -> output byte-identical to R7.
#define NCHUNK 7
#define CLEN   50
#define NPF    10                 // ring depth; 50/100/150 all %10==0

// ---------------------------------------------------------------------------
// K12: fused bitpack (blocks 0..2335) + W1 half-split pack (2336..3503) +
//      dummy-zero-row fill (block 3504). Bitpack float4 streaming.
__global__ __launch_bounds__(384) void k12(const float* __restrict__ x,
                                           const float* __restrict__ W1,
                                           uint32_t* __restrict__ bits1,
                                           float* __restrict__ W1s) {
    __shared__ float lds[32 * T_SZ];   // 44.8 KB
    const int bid = blockIdx.x;
    const int tid = threadIdx.x;
    if (bid < NW32 * B_SZ) {
        // --- bitpack: block = (b, w); contiguous rowsx350 tile -> LDS -> pack
        const int w = bid % NW32;
        const int b = bid / NW32;
        const int rows = (NIN - (w << 5) < 32) ? (NIN - (w << 5)) : 32;  // 32 or 8
        const float* base = x + ((size_t)(b * NIN + (w << 5))) * T_SZ;
        const int nf4 = (rows * T_SZ) >> 2;     // rows even -> divisible by 4
        for (int f = tid; f < nf4; f += 384)
            ((float4*)lds)[f] = ((const float4*)base)[f];
        __syncthreads();
        if (tid < T_SZ) {
            uint32_t bits = 0;
            for (int j = 0; j < rows; ++j)
                bits |= (lds[j * T_SZ + tid] > 0.5f) ? (1u << j) : 0u;
            bits1[(size_t)(b * T_SZ + tid) * NW32 + w] = bits;
        }
    } else if (bid < NW32 * B_SZ + NW32 * 16) {
        // --- pack W1 [512, 2312] -> W1s[h][i][256], h = o>>8
        float (*tile)[33] = (float (*)[33])lds;
        const int bb = bid - NW32 * B_SZ;
        const int i0 = (bb % NW32) * 32, o0 = (bb / NW32) * 32;
        const int tx = tid & 31, ty = tid >> 5;  // ty 0..11
#pragma unroll
        for (int r = 0; r < 3; ++r) {
            int row = ty + 12 * r;
            if (row < 32) {
                int o = o0 + row, i = i0 + tx;
                if (i < NIN) tile[row][tx] = W1[(size_t)o * NIN + i];
            }
        }
        __syncthreads();
#pragma unroll
        for (int r = 0; r < 3; ++r) {
            int row = ty + 12 * r;
            if (row < 32) {
                int i = i0 + row, o = o0 + tx;
                if (i < NIN)
                    W1s[((size_t)(o >> 8) * NROW + i) * NHALF + (o & 255)] = tile[tx][row];
            }
        }
    } else {
        // --- dummy zero row i = NIN for both halves
        if (tid < NHALF) {
            W1s[((size_t)0 * NROW + NIN) * NHALF + tid] = 0.0f;
            W1s[((size_t)1 * NROW + NIN) * NHALF + tid] = 0.0f;
        }
    }
}

// ---------------------------------------------------------------------------
// K3: sparse dense1 (R6/R10 gather form — the measured optimum: 101us,
// 26.3 TB/s L2-gather = 76% of streaming ubench). Half-split for L2
// residency; single-wave shfl prefix scan; branch-free 4-deep pipelined row
// loop via dummy zero-row padding. R13: L2-HIT-SERVICE-RATE bound ->
// structural ceiling given the bit-exact sum order. Do not touch.
__global__ __launch_bounds__(256) void k3_dense1(const uint32_t* __restrict__ bits1,
                                                 const float* __restrict__ W1s,
                                                 float* __restrict__ z1ct) {
    __shared__ uint32_t words[128];
    __shared__ uint16_t pfx[80];
    __shared__ uint16_t idxbuf[NIN + 16];
    __shared__ float red[3][NHALF];
    __shared__ float fin[NHALF];

    const int id = blockIdx.x;
    const int h = (id >> 2) & 1;                  // XCD-affine half select
    const int bt = ((id >> 3) << 2) | (id & 3);   // b*350 + t (bijective)
    const int tid = threadIdx.x;
    const int wv = tid >> 6, lane = tid & 63;

    if (tid < 128) words[tid] = (tid < NW32) ? bits1[(size_t)bt * NW32 + tid] : 0u;
    __syncthreads();

    if (wv == 0) {
        uint32_t w0 = words[lane];
        uint32_t w1 = words[lane + 64];
        int p0 = __popc(w0), p1 = __popc(w1);
        int s0 = p0, s1 = p1;
#pragma unroll
        for (int off = 1; off < 64; off <<= 1) {
            int u0 = __shfl_up(s0, off);
            int u1 = __shfl_up(s1, off);
            if (lane >= off) { s0 += u0; s1 += u1; }
        }
        int tot0 = __shfl(s0, 63);
        pfx[lane] = (uint16_t)(s0 - p0);
        if (lane < 9) pfx[lane + 64] = (uint16_t)(tot0 + s1 - p1);
        if (lane == 8) pfx[73] = (uint16_t)(tot0 + s1);   // ntot
    }
    __syncthreads();

    const int ntot = pfx[73];
    const int npad = (ntot + 15) & ~15;
    if (tid < NW32) {
        uint32_t m = words[tid];
        int p = pfx[tid];
        while (m) {
            int j = __builtin_ctz(m);
            m &= m - 1;
            idxbuf[p++] = (uint16_t)((tid << 5) + j);
        }
    }
    if (tid >= 240) {                   // pad to multiple of 16 with zero row
        int k = tid - 240;
        if (ntot + k < npad) idxbuf[ntot + k] = (uint16_t)NIN;
    }
    __syncthreads();

    const float* Wh = W1s + (size_t)h * NROW * NHALF;
    float4 acc = make_float4(0.f, 0.f, 0.f, 0.f);
    for (int r = wv; r < npad; r += 16) {
        int i0 = idxbuf[r], i1 = idxbuf[r + 4], i2 = idxbuf[r + 8], i3 = idxbuf[r + 12];
        float4 v0 = ((const float4*)(Wh + (size_t)i0 * NHALF))[lane];
        float4 v1 = ((const float4*)(Wh + (size_t)i1 * NHALF))[lane];
        float4 v2 = ((const float4*)(Wh + (size_t)i2 * NHALF))[lane];
        float4 v3 = ((const float4*)(Wh + (size_t)i3 * NHALF))[lane];
        acc.x += v0.x; acc.y += v0.y; acc.z += v0.z; acc.w += v0.w;
        acc.x += v1.x; acc.y += v1.y; acc.z += v1.z; acc.w += v1.w;
        acc.x += v2.x; acc.y += v2.y; acc.z += v2.z; acc.w += v2.w;
        acc.x += v3.x; acc.y += v3.y; acc.z += v3.z; acc.w += v3.w;
    }
    if (wv > 0) ((float4*)red[wv - 1])[lane] = acc;
    __syncthreads();
    if (wv == 0) {
        float4 a1 = ((float4*)red[0])[lane];
        float4 a2 = ((float4*)red[1])[lane];
        float4 a3 = ((float4*)red[2])[lane];
        acc.x = ((acc.x + a1.x) + a2.x) + a3.x;
        acc.y = ((acc.y + a1.y) + a2.y) + a3.y;
        acc.z = ((acc.z + a1.z) + a2.z) + a3.z;
        acc.w = ((acc.w + a1.w) + a2.w) + a3.w;
        ((float4*)fin)[lane] = acc;
    }
    __syncthreads();
    const int och = (h << 8) + tid;
    const int oc = och >> 6, l6 = och & 63;
    const int b = bt / T_SZ, t = bt - b * T_SZ;
    z1ct[((size_t)(b * NW64 + oc) * T_SZ + t) * 64 + l6] = fin[tid];
}

// ---------------------------------------------------------------------------
// K45: fused layer-1 scan + dense2, DUAL-CHAIN (R23). 256 threads = 4 waves;
// wave wv scans channel groups 2wv and 2wv+1 — two independent recurrences
// interleaved per lane (2x dep-chain ILP, zero extra work). Branch-free
// refills (R19); exact 100-step warm-up; per-chain math, two ballots/step,
// dense2 per-(t,o) order identical to R7 -> output byte-identical.
__global__ __launch_bounds__(256) void k45(const float* __restrict__ z1ct,
                                           const float* __restrict__ W2,
                                           float* __restrict__ z2ct) {
    __shared__ float W2s[NHID * NOUT];      // [c][o], 20 KB
    __shared__ uint64_t sw[CLEN][NW64];     // s1 ballot words for my 50 t's
    const int tid = threadIdx.x;
    const int wv = tid >> 6, lane = tid & 63;   // wv 0..3
    const int b = blockIdx.x / NCHUNK;
    const int ck = blockIdx.x % NCHUNK;
    const int tstart = ck * CLEN;
    const int tend = tstart + CLEN;
    const int t0 = (tstart >= 100) ? tstart - 100 : 0;

    for (int k = tid; k < NHID * NOUT; k += 256) {
        int c = k / NOUT, o = k - c * NOUT;
        W2s[k] = W2[(size_t)o * NHID + c];
    }

    const int ga = 2 * wv, gb = 2 * wv + 1;
    const float* baseA = z1ct + (size_t)(b * NW64 + ga) * T_SZ * 64 + lane;
    const float* baseB = z1ct + (size_t)(b * NW64 + gb) * T_SZ * 64 + lane;

    double Aa = 0.0, Ba = 0.0, A2a = 0.0, B2a = 0.0;
    double Ab = 0.0, Bb = 0.0, A2b = 0.0, B2b = 0.0;
    float raa = 0.0f, rba = 0.0f, rab = 0.0f, rbb = 0.0f;
    const double TAIL = D100_D * CS_D;
    float xa[NPF], xda[NPF], xb2[NPF], xdb2[NPF];
#pragma unroll
    for (int i = 0; i < NPF; ++i) {
        const int t = t0 + i;                       // < 350: always valid
        xa[i]  = baseA[(size_t)t * 64];
        xb2[i] = baseB[(size_t)t * 64];
        const int td = t - 100;
        const int tdc = (td >= 0) ? td : 0;
        float vda = baseA[(size_t)tdc * 64];        // unconditional
        float vdb = baseB[(size_t)tdc * 64];
        xda[i]  = (td >= 0) ? vda : 0.0f;           // select, no branch
        xdb2[i] = (td >= 0) ? vdb : 0.0f;
    }
    for (int tb = t0; tb < tend; tb += NPF) {
        uint64_t mba[NPF], mbb[NPF];
#pragma unroll
        for (int i = 0; i < NPF; ++i) {
            const int t = tb + i;
            float x1 = xa[i],  xd1 = xda[i];
            float x2 = xb2[i], xd2 = xdb2[i];
            const int tn = t + NPF;
            const int tcl = (tn < T_SZ) ? tn : (T_SZ - 1);
            float vb1 = baseA[(size_t)tcl * 64];    // unconditional (clamped)
            float vb2 = baseB[(size_t)tcl * 64];
            xa[i]  = (tn < T_SZ) ? vb1 : 0.0f;
            xb2[i] = (tn < T_SZ) ? vb2 : 0.0f;
            const int td = tn - 100;
            const int tdc = (td >= 0) ? td : 0;
            float vd1 = baseA[(size_t)tdc * 64];    // unconditional (clamped)
            float vd2 = baseB[(size_t)tdc * 64];
            xda[i]  = (td >= 0) ? vd1 : 0.0f;
            xdb2[i] = (td >= 0) ? vd2 : 0.0f;
            // ---- chain A (math identical to R7 single-chain)
            Ba = DS_D * Ba + DS_D * Aa;
            Aa = DS_D * Aa + (double)x1;
            B2a = DS_D * B2a + DS_D * A2a;
            A2a = DS_D * A2a + (double)xd1;
            double ya = CS_D * Ba - TAIL * (B2a + 100.0 * A2a);
            float ua = (float)ya + CREF_F * rba;
            float sa = (ua >= 10.0f) ? 1.0f : 0.0f;
            float rana = DREF_F * raa + sa;
            float rbna = DREF_F * rba + DREF_F * raa;
            raa = rana; rba = rbna;
            // ---- chain B (independent -> interleaves in the pipeline)
            Bb = DS_D * Bb + DS_D * Ab;
            Ab = DS_D * Ab + (double)x2;
            B2b = DS_D * B2b + DS_D * A2b;
            A2b = DS_D * A2b + (double)xd2;
            double yb = CS_D * Bb - TAIL * (B2b + 100.0 * A2b);
            float ub = (float)yb + CREF_F * rbb;
            float sb = (ub >= 10.0f) ? 1.0f : 0.0f;
            float ranb = DREF_F * rab + sb;
            float rbnb = DREF_F * rbb + DREF_F * rab;
            rab = ranb; rbb = rbnb;
            mba[i] = __ballot(sa != 0.0f);
            mbb[i] = __ballot(sb != 0.0f);
        }
        // uniform per-tb flush: (tstart - t0) % NPF == 0
        if (tb >= tstart && lane == 0) {
#pragma unroll
            for (int i = 0; i < NPF; ++i) {
                sw[tb - tstart + i][ga] = mba[i];
                sw[tb - tstart + i][gb] = mbb[i];
            }
        }
    }
    __syncthreads();

    // ---- dense2: 500 (t,o) pairs over 256 threads; per-(t,o) accumulation
    // order identical to R7 -> z2ct bytes identical.
    for (int k = tid; k < CLEN * NOUT; k += 256) {
        const int tr = k / NOUT;
        const int o = k - tr * NOUT;
        const int t = tstart + tr;
        float acc = 0.f;
#pragma unroll
        for (int w2 = 0; w2 < NW64; ++w2) {
            uint64_t m = sw[tr][w2];
            while (m) {
                int j = __builtin_ctzll(m);
                m &= m - 1;
                acc += W2s[((w2 << 6) + j) * NOUT + o];
            }
        }
        const int bo = b * NOUT + o;
        z2ct[((size_t)(bo >> 6) * T_SZ + t) * 64 + (bo & 63)] = acc;
    }
}

// ---------------------------------------------------------------------------
// K6: fused psp-IIR + refractory scan, layer 2, chunked (R7-proven form,
// byte-identical). Branch-free refills + uniform flushes.
__global__ __launch_bounds__(64) void k6_fir_scan2(const float* __restrict__ z2ct,
                                                   float* __restrict__ out) {
    const int lane = threadIdx.x;
    const int g = blockIdx.x / NCHUNK;    // bo group 0..4
    const int ck = blockIdx.x % NCHUNK;
    const int tstart = ck * CLEN;
    const int tend = tstart + CLEN;
    const int t0 = (tstart >= 100) ? tstart - 100 : 0;
    const int bo = (g << 6) + lane;       // 0..319
    const float* base = z2ct + (size_t)g * T_SZ * 64 + lane;
    float* op = out + (size_t)bo * T_SZ;
    double A = 0.0, Bs = 0.0, A2 = 0.0, Bs2 = 0.0;
    float ra = 0.0f, rb = 0.0f;
    const double TAIL = D100_D * CS_D;
    float xb[NPF], xdb[NPF];
#pragma unroll
    for (int i = 0; i < NPF; ++i) {
        const int t = t0 + i;
        xb[i] = base[(size_t)t * 64];
        const int td = t - 100;
        const int tdc = (td >= 0) ? td : 0;
        float vd = base[(size_t)tdc * 64];
        xdb[i] = (td >= 0) ? vd : 0.0f;
    }
    for (int tb = t0; tb < tend; tb += NPF) {
        float sb[NPF];
#pragma unroll
        for (int i = 0; i < NPF; ++i) {
            const int t = tb + i;
            float x = xb[i], xd = xdb[i];
            const int tn = t + NPF;
            const int tcl = (tn < T_SZ) ? tn : (T_SZ - 1);
            float vb = base[(size_t)tcl * 64];
            xb[i] = (tn < T_SZ) ? vb : 0.0f;
            const int td = tn - 100;
            const int tdc = (td >= 0) ? td : 0;
            float vd = base[(size_t)tdc * 64];
            xdb[i] = (td >= 0) ? vd : 0.0f;
            Bs = DS_D * Bs + DS_D * A;
            A = DS_D * A + (double)x;
            Bs2 = DS_D * Bs2 + DS_D * A2;
            A2 = DS_D * A2 + (double)xd;
            double y = CS_D * Bs - TAIL * (Bs2 + 100.0 * A2);
            float u = (float)y + CREF_F * rb;
            float s = (u >= 10.0f) ? 1.0f : 0.0f;
            float ran = DREF_F * ra + s;
            float rbn = DREF_F * rb + DREF_F * ra;
            ra = ran; rb = rbn;
            sb[i] = s;
        }
        if (tb >= tstart) {                 // uniform per-tb flush
#pragma unroll
            for (int i = 0; i < NPF; ++i)
                op[tb + i] = sb[i];
        }
    }
}

// ---------------------------------------------------------------------------
extern "C" void kernel_launch(void* const* d_in, const int* in_sizes, int n_in,
                              void* d_out, int out_size, void* d_ws, size_t ws_size,
                              hipStream_t stream) {
    const float* spikeInput = (const float*)d_in[0];  // [32, 2312, 350]
    const float* W1 = (const float*)d_in[1];          // [512, 2312]
    const float* W2 = (const float*)d_in[2];          // [10, 512]
    float* out = (float*)d_out;                       // [32, 10, 350]

    char* ws = (char*)d_ws;
    float* W1s = (float*)(ws + 0);                        //  4,737,024 B (2313 rows x 2 halves)
    uint32_t* bits1 = (uint32_t*)(ws + 4737024);          //  3,270,400 B
    float* z1ct = (float*)(ws + 8007424);                 // 22,937,600 B
    // z2ct aliases bits1's region: bits1 is dead after k3, z2ct written by k45.
    float* z2ct = (float*)(ws + 4737024);                 //    448,000 B (alias)
    // total: 30,945,024 B

    k12<<<NW32 * B_SZ + NW32 * 16 + 1, 384, 0, stream>>>(spikeInput, W1, bits1, W1s);
    k3_dense1<<<B_SZ * T_SZ * 2, 256, 0, stream>>>(bits1, W1s, z1ct);
    k45<<<B_SZ * NCHUNK, 256, 0, stream>>>(z1ct, W2, z2ct);
    k6_fir_scan2<<<5 * NCHUNK, 64, 0, stream>>>(z2ct, out);
}